// Round 6
// baseline (79.902 us; speedup 1.0000x reference)
//
#include <hip/hip_runtime.h>

#define MAX_DISP 48

// Geometry fixed by reference: n=2, c=32, h=128, w=256
// out[n][c][d][h][x] = (x>=d) ? l[n][c][h][x] - r[n][c][h][x-d] : 1.0f
// out shape (n, c, MAX_DISP, h, w) float32 = 402.7 MB -> write-BW bound.
//
// R5: same minimal-read structure as R4 (r staged in LDS once, l in regs,
// one d-residue class per wave, sliding conflict-free b128 window), but each
// block now covers 8 consecutive h rows (HG=8). Each (wave, d) then writes
// an 8 KB CONTIGUOUS run (8 adjacent h-rows of one d-plane) instead of
// 1 KB runs strided 128 KB apart — testing whether write-run length closes
// the 6.05 -> ~6.9 TB/s gap to the pure-fill rate.

constexpr int W  = 256;
constexpr int H  = 128;
constexpr int D  = MAX_DISP;   // 48
constexpr int HW = H * W;
constexpr int HG = 8;          // h rows per block

typedef float vf4 __attribute__((ext_vector_type(4)));

template <int WAVE>
__device__ __forceinline__ void run_passes(const vf4* __restrict__ rs4,
                                           int lane, int xq,
                                           const vf4* __restrict__ lv,
                                           float* __restrict__ obase)
{
    // Per-row sliding window over the staged r rows.
    // At pass k (d = WAVE + 4k): whi[r] = rs4[r][lane-k] (clamped),
    // wlo[r] = rs4[r][lane-k-1]. Needed value for output j is
    // rs[xq + j - d] -> compile-time slot 4 + j - WAVE of {wlo,whi}.
    vf4 wlo[HG], whi[HG];
    #pragma unroll
    for (int rr = 0; rr < HG; ++rr) {
        wlo[rr] = rs4[rr * 64 + max(lane - 1, 0)];
        whi[rr] = rs4[rr * 64 + lane];
    }

    for (int k = 0; k < 12; ++k) {
        const int d = WAVE + 4 * k;
        float* __restrict__ od = obase + (size_t)d * HW + xq;

        #pragma unroll
        for (int rr = 0; rr < HG; ++rr) {
            float rv0, rv1, rv2, rv3;
            if constexpr (WAVE == 0) { rv0 = whi[rr].x; rv1 = whi[rr].y; rv2 = whi[rr].z; rv3 = whi[rr].w; }
            else if constexpr (WAVE == 1) { rv0 = wlo[rr].w; rv1 = whi[rr].x; rv2 = whi[rr].y; rv3 = whi[rr].z; }
            else if constexpr (WAVE == 2) { rv0 = wlo[rr].z; rv1 = wlo[rr].w; rv2 = whi[rr].x; rv3 = whi[rr].y; }
            else                          { rv0 = wlo[rr].y; rv1 = wlo[rr].z; rv2 = wlo[rr].w; rv3 = whi[rr].x; }

            vf4 o;
            o.x = (xq + 0 >= d) ? lv[rr].x - rv0 : 1.0f;
            o.y = (xq + 1 >= d) ? lv[rr].y - rv1 : 1.0f;
            o.z = (xq + 2 >= d) ? lv[rr].z - rv2 : 1.0f;
            o.w = (xq + 3 >= d) ? lv[rr].w - rv3 : 1.0f;

            __builtin_nontemporal_store(o, reinterpret_cast<vf4*>(od + rr * W));
        }

        if (k < 11) {                          // slide all row-windows by 4
            const int src = max(lane - k - 2, 0);
            #pragma unroll
            for (int rr = 0; rr < HG; ++rr) {
                whi[rr] = wlo[rr];
                wlo[rr] = rs4[rr * 64 + src];
            }
        }
    }
}

__global__ __launch_bounds__(256) void cost_volume_kernel(
    const float* __restrict__ l,
    const float* __restrict__ r,
    float* __restrict__ out)
{
    const int b  = blockIdx.x;            // nc*(H/HG) + hg, in [0, 1024)
    const int hg = b & (H / HG - 1);      // 0..15
    const int nc = b >> 4;
    const int h0 = hg * HG;

    __shared__ float rs[HG * W];          // 8 KB

    const int t    = threadIdx.x;
    const int wave = t >> 6;
    const int lane = t & 63;
    const int xq   = lane << 2;

    // Stage 8 r rows as float4 (512 float4s, 2 per thread).
    const vf4* __restrict__ rsrc =
        reinterpret_cast<const vf4*>(r + (size_t)(nc * H + h0) * W);
    vf4* rdst = reinterpret_cast<vf4*>(rs);
    rdst[t]       = rsrc[t];
    rdst[t + 256] = rsrc[t + 256];

    // l quads for the 8 rows, held in registers (L1/L2-cached re-reads
    // across the 4 waves).
    vf4 lv[HG];
    #pragma unroll
    for (int rr = 0; rr < HG; ++rr)
        lv[rr] = *reinterpret_cast<const vf4*>(
            l + (size_t)(nc * H + h0 + rr) * W + xq);

    float* obase = out + (size_t)nc * D * HW + (size_t)h0 * W;

    __syncthreads();

    const vf4* rs4 = reinterpret_cast<const vf4*>(rs);
    switch (wave) {                       // wave-uniform branch
        case 0: run_passes<0>(rs4, lane, xq, lv, obase); break;
        case 1: run_passes<1>(rs4, lane, xq, lv, obase); break;
        case 2: run_passes<2>(rs4, lane, xq, lv, obase); break;
        default: run_passes<3>(rs4, lane, xq, lv, obase); break;
    }
}

extern "C" void kernel_launch(void* const* d_in, const int* in_sizes, int n_in,
                              void* d_out, int out_size, void* d_ws, size_t ws_size,
                              hipStream_t stream)
{
    const float* l = (const float*)d_in[0];
    const float* r = (const float*)d_in[1];
    float* out = (float*)d_out;

    const int nBlk = 64 * (H / HG);       // 1024
    cost_volume_kernel<<<nBlk, 256, 0, stream>>>(l, r, out);
}

// Round 7
// 79.901 us; speedup vs baseline: 1.0000x; 1.0000x over previous
//
#include <hip/hip_runtime.h>

#define MAX_DISP 48

// Geometry fixed by reference: n=2, c=32, h=128, w=256
// out[n][c][d][h][x] = (x>=d) ? l[n][c][h][x] - r[n][c][h][x-d] : 1.0f
// out shape (n, c, MAX_DISP, h, w) float32 = 402.7 MB -> write-BW bound.
//
// R6 = R4 (best: 69.3us) with ONE change: plain float4 stores instead of
// __builtin_nontemporal_store. A/B test: the harness fill kernels sustain
// 6.9-7.1 TB/s pure-write on this buffer with plain stores; R4+NT achieved
// 6.05 TB/s effective. Testing whether NT streaming bypasses L2
// write-combining and costs ~10%.
//
// Structure: one block per (n,c,h) row. r row staged in LDS once; l quad in
// registers; each wave owns one d residue class (d = wave + 4k). Within a
// wave d is uniform, so the shifted r window slides by exactly 4 words per
// pass: one aligned, conflict-free ds_read_b128 per pass.

constexpr int W  = 256;
constexpr int H  = 128;
constexpr int D  = MAX_DISP;   // 48
constexpr int HW = H * W;

typedef float vf4 __attribute__((ext_vector_type(4)));

template <int WAVE>
__device__ __forceinline__ void run_passes(const vf4* __restrict__ rs4,
                                           int lane, int xq, vf4 lv,
                                           float* __restrict__ obase)
{
    // Window at pass k covers r words [xq-4k-4, xq-4k+3]:
    //   wlo = rs[xq-4k-4 .. xq-4k-1], whi = rs[xq-4k .. xq-4k+3]
    // Needed value for output j: rs[xq+j-d], d = WAVE+4k -> window slot
    // 4 + j - WAVE (compile-time). Clamped (index<0) slots are only
    // selected when x<d, where the mask writes 1.0 anyway.
    vf4 wlo = rs4[max(lane - 1, 0)];
    vf4 whi = rs4[lane];

    #pragma unroll
    for (int k = 0; k < 12; ++k) {
        const int d = WAVE + 4 * k;

        float rv0, rv1, rv2, rv3;
        if constexpr (WAVE == 0) { rv0 = whi.x; rv1 = whi.y; rv2 = whi.z; rv3 = whi.w; }
        else if constexpr (WAVE == 1) { rv0 = wlo.w; rv1 = whi.x; rv2 = whi.y; rv3 = whi.z; }
        else if constexpr (WAVE == 2) { rv0 = wlo.z; rv1 = wlo.w; rv2 = whi.x; rv3 = whi.y; }
        else                          { rv0 = wlo.y; rv1 = wlo.z; rv2 = wlo.w; rv3 = whi.x; }

        vf4 o;
        o.x = (xq + 0 >= d) ? lv.x - rv0 : 1.0f;
        o.y = (xq + 1 >= d) ? lv.y - rv1 : 1.0f;
        o.z = (xq + 2 >= d) ? lv.z - rv2 : 1.0f;
        o.w = (xq + 3 >= d) ? lv.w - rv3 : 1.0f;

        *reinterpret_cast<vf4*>(obase + (size_t)d * HW + xq) = o;  // plain store

        if (k < 11) {                       // slide window down by 4 words
            whi = wlo;
            wlo = rs4[max(lane - k - 2, 0)];
        }
    }
}

__global__ __launch_bounds__(256) void cost_volume_kernel(
    const float* __restrict__ l,
    const float* __restrict__ r,
    float* __restrict__ out)
{
    const int row = blockIdx.x;           // nc*H + h, in [0, 8192)
    const int h   = row % H;
    const int nc  = row / H;

    __shared__ float rs[W];

    const int t    = threadIdx.x;
    const int wave = t >> 6;              // 0..3  (uniform within a wave)
    const int lane = t & 63;
    const int xq   = lane << 2;           // quad base column

    const float* __restrict__ lrow = l + (size_t)row * W;
    const float* __restrict__ rrow = r + (size_t)row * W;

    rs[t] = rrow[t];

    const vf4 lv = *reinterpret_cast<const vf4*>(lrow + xq);
    float* obase = out + (size_t)nc * D * HW + (size_t)h * W;

    __syncthreads();

    const vf4* rs4 = reinterpret_cast<const vf4*>(rs);
    switch (wave) {                       // wave-uniform branch
        case 0: run_passes<0>(rs4, lane, xq, lv, obase); break;
        case 1: run_passes<1>(rs4, lane, xq, lv, obase); break;
        case 2: run_passes<2>(rs4, lane, xq, lv, obase); break;
        default: run_passes<3>(rs4, lane, xq, lv, obase); break;
    }
}

extern "C" void kernel_launch(void* const* d_in, const int* in_sizes, int n_in,
                              void* d_out, int out_size, void* d_ws, size_t ws_size,
                              hipStream_t stream)
{
    const float* l = (const float*)d_in[0];
    const float* r = (const float*)d_in[1];
    float* out = (float*)d_out;

    const int nRows = 2 * 32 * H;         // 8192
    cost_volume_kernel<<<nRows, 256, 0, stream>>>(l, r, out);
}

// Round 8
// 77.452 us; speedup vs baseline: 1.0316x; 1.0316x over previous
//
#include <hip/hip_runtime.h>

#define MAX_DISP 48

// Geometry fixed by reference: n=2, c=32, h=128, w=256
// out[n][c][d][h][x] = (x>=d) ? l[n][c][h][x] - r[n][c][h][x-d] : 1.0f
// out shape (n, c, MAX_DISP, h, w) float32 = 402.7 MB -> write-BW bound.
//
// R7 = R4 re-partitioned: wave <-> h-row (4 rows/block), each wave loops
// over ALL 48 d (fully unrolled, so the sliding-window selects stay
// compile-time via d&3). At each step the block's 4 waves write 4 ADJACENT
// rows of the SAME d-plane -> 4 KB instantaneous write contiguity (vs
// R4's 4x1KB across 4 planes). Per-thread state identical to R4
// (lv/whi/wlo), NT stores kept (R6 proved plain stores cost +10.6us).

constexpr int W  = 256;
constexpr int H  = 128;
constexpr int D  = MAX_DISP;   // 48
constexpr int HW = H * W;
constexpr int RPB = 4;         // rows (= waves) per block

typedef float vf4 __attribute__((ext_vector_type(4)));

__global__ __launch_bounds__(256) void cost_volume_kernel(
    const float* __restrict__ l,
    const float* __restrict__ r,
    float* __restrict__ out)
{
    const int b    = blockIdx.x;             // nc*(H/RPB) + hq, in [0, 2048)
    const int hq   = b & (H / RPB - 1);      // 0..31
    const int nc   = b >> 5;
    const int t    = threadIdx.x;
    const int wave = t >> 6;                 // 0..3 -> row within group
    const int lane = t & 63;
    const int xq   = lane << 2;
    const int h    = hq * RPB + wave;
    const int row  = nc * H + h;

    __shared__ float rs[RPB * W];            // 4 KB, one row per wave

    // Wave-private staging of this wave's r row (vf4 per lane).
    vf4* rs4w = reinterpret_cast<vf4*>(rs) + wave * 64;
    rs4w[lane] = reinterpret_cast<const vf4*>(r + (size_t)row * W)[lane];

    const vf4 lv = reinterpret_cast<const vf4*>(l + (size_t)row * W)[lane];

    float* obase = out + (size_t)nc * D * HW + (size_t)h * W + xq;

    __syncthreads();                         // (safety; LDS is wave-private)

    // Sliding window: before pass d (m = d>>2): whi = rs4w[lane-m],
    // wlo = rs4w[lane-m-1] (clamped; clamped slots only feed masked lanes).
    // Value for output j is rs[xq+j-d] -> compile-time slot of {wlo,whi}.
    vf4 whi = rs4w[lane];
    vf4 wlo = rs4w[max(lane - 1, 0)];

    #pragma unroll
    for (int d = 0; d < D; ++d) {
        const int ph = d & 3;

        float rv0, rv1, rv2, rv3;
        if (ph == 0)      { rv0 = whi.x; rv1 = whi.y; rv2 = whi.z; rv3 = whi.w; }
        else if (ph == 1) { rv0 = wlo.w; rv1 = whi.x; rv2 = whi.y; rv3 = whi.z; }
        else if (ph == 2) { rv0 = wlo.z; rv1 = wlo.w; rv2 = whi.x; rv3 = whi.y; }
        else              { rv0 = wlo.y; rv1 = wlo.z; rv2 = wlo.w; rv3 = whi.x; }

        vf4 o;
        o.x = (xq + 0 >= d) ? lv.x - rv0 : 1.0f;
        o.y = (xq + 1 >= d) ? lv.y - rv1 : 1.0f;
        o.z = (xq + 2 >= d) ? lv.z - rv2 : 1.0f;
        o.w = (xq + 3 >= d) ? lv.w - rv3 : 1.0f;

        __builtin_nontemporal_store(
            o, reinterpret_cast<vf4*>(obase + (size_t)d * HW));

        if (ph == 3 && d < D - 1) {          // slide window down by 4 words
            whi = wlo;
            wlo = rs4w[max(lane - (d >> 2) - 2, 0)];
        }
    }
}

extern "C" void kernel_launch(void* const* d_in, const int* in_sizes, int n_in,
                              void* d_out, int out_size, void* d_ws, size_t ws_size,
                              hipStream_t stream)
{
    const float* l = (const float*)d_in[0];
    const float* r = (const float*)d_in[1];
    float* out = (float*)d_out;

    const int nBlk = 64 * (H / RPB);         // 2048
    cost_volume_kernel<<<nBlk, 256, 0, stream>>>(l, r, out);
}

// Round 9
// 68.737 us; speedup vs baseline: 1.1624x; 1.1268x over previous
//
#include <hip/hip_runtime.h>

#define MAX_DISP 48

// Geometry fixed by reference: n=2, c=32, h=128, w=256
// out[n][c][d][h][x] = (x>=d) ? l[n][c][h][x] - r[n][c][h][x-d] : 1.0f
// out shape (n, c, MAX_DISP, h, w) float32 = 402.7 MB -> write-BW bound.
//
// FINAL (R4 structure, best = 69.3us, 6.05 TB/s effective = 96% of the
// m13 mixed-stream ceiling). Probes that regressed and were reverted:
//   R5 8-row blocking      -> 79.9us (occupancy/VGPR pressure)
//   R6 plain stores        -> 79.9us (L2 write-allocate thrash; NT wins)
//   R7 wave<->row mapping  -> 77.5us (worse per-wave store stride)
//
// Structure: one block per (n,c,h) row. r row staged in LDS once; l quad in
// registers; each wave owns one d residue class (d = wave + 4k). Within a
// wave d is uniform, so the shifted r window slides by exactly 4 words per
// pass: one aligned, conflict-free ds_read_b128 per pass. Nontemporal
// stores keep the 403MB write stream out of L2.

constexpr int W  = 256;
constexpr int H  = 128;
constexpr int D  = MAX_DISP;   // 48
constexpr int HW = H * W;

typedef float vf4 __attribute__((ext_vector_type(4)));

template <int WAVE>
__device__ __forceinline__ void run_passes(const vf4* __restrict__ rs4,
                                           int lane, int xq, vf4 lv,
                                           float* __restrict__ obase)
{
    // Window at pass k covers r words [xq-4k-4, xq-4k+3]:
    //   wlo = rs[xq-4k-4 .. xq-4k-1], whi = rs[xq-4k .. xq-4k+3]
    // Needed value for output j: rs[xq+j-d], d = WAVE+4k -> window slot
    // 4 + j - WAVE (compile-time). Clamped (index<0) slots are only
    // selected when x<d, where the mask writes 1.0 anyway.
    vf4 wlo = rs4[max(lane - 1, 0)];
    vf4 whi = rs4[lane];

    #pragma unroll
    for (int k = 0; k < 12; ++k) {
        const int d = WAVE + 4 * k;

        float rv0, rv1, rv2, rv3;
        if constexpr (WAVE == 0) { rv0 = whi.x; rv1 = whi.y; rv2 = whi.z; rv3 = whi.w; }
        else if constexpr (WAVE == 1) { rv0 = wlo.w; rv1 = whi.x; rv2 = whi.y; rv3 = whi.z; }
        else if constexpr (WAVE == 2) { rv0 = wlo.z; rv1 = wlo.w; rv2 = whi.x; rv3 = whi.y; }
        else                          { rv0 = wlo.y; rv1 = wlo.z; rv2 = wlo.w; rv3 = whi.x; }

        vf4 o;
        o.x = (xq + 0 >= d) ? lv.x - rv0 : 1.0f;
        o.y = (xq + 1 >= d) ? lv.y - rv1 : 1.0f;
        o.z = (xq + 2 >= d) ? lv.z - rv2 : 1.0f;
        o.w = (xq + 3 >= d) ? lv.w - rv3 : 1.0f;

        __builtin_nontemporal_store(
            o, reinterpret_cast<vf4*>(obase + (size_t)d * HW + xq));

        if (k < 11) {                       // slide window down by 4 words
            whi = wlo;
            wlo = rs4[max(lane - k - 2, 0)];
        }
    }
}

__global__ __launch_bounds__(256) void cost_volume_kernel(
    const float* __restrict__ l,
    const float* __restrict__ r,
    float* __restrict__ out)
{
    const int row = blockIdx.x;           // nc*H + h, in [0, 8192)
    const int h   = row % H;
    const int nc  = row / H;

    __shared__ float rs[W];

    const int t    = threadIdx.x;
    const int wave = t >> 6;              // 0..3  (uniform within a wave)
    const int lane = t & 63;
    const int xq   = lane << 2;           // quad base column

    const float* __restrict__ lrow = l + (size_t)row * W;
    const float* __restrict__ rrow = r + (size_t)row * W;

    rs[t] = rrow[t];

    const vf4 lv = *reinterpret_cast<const vf4*>(lrow + xq);
    float* obase = out + (size_t)nc * D * HW + (size_t)h * W;

    __syncthreads();

    const vf4* rs4 = reinterpret_cast<const vf4*>(rs);
    switch (wave) {                       // wave-uniform branch
        case 0: run_passes<0>(rs4, lane, xq, lv, obase); break;
        case 1: run_passes<1>(rs4, lane, xq, lv, obase); break;
        case 2: run_passes<2>(rs4, lane, xq, lv, obase); break;
        default: run_passes<3>(rs4, lane, xq, lv, obase); break;
    }
}

extern "C" void kernel_launch(void* const* d_in, const int* in_sizes, int n_in,
                              void* d_out, int out_size, void* d_ws, size_t ws_size,
                              hipStream_t stream)
{
    const float* l = (const float*)d_in[0];
    const float* r = (const float*)d_in[1];
    float* out = (float*)d_out;

    const int nRows = 2 * 32 * H;         // 8192
    cost_volume_kernel<<<nRows, 256, 0, stream>>>(l, r, out);
}